// Round 12
// baseline (1004.702 us; speedup 1.0000x reference)
//
#include <hip/hip_runtime.h>
#include <hip/hip_bf16.h>
#include <stdint.h>

#define B_  2048
#define T_  16
#define F_  768
#define H_  1024
#define G4_ 4096   // 4*H
#define TF_ (T_ * F_)   // 12288

typedef __attribute__((ext_vector_type(8))) __bf16 bf16x8;
typedef __attribute__((ext_vector_type(4))) float  f32x4;

static __device__ __forceinline__ unsigned short f2bf(float f) {
    union { float f; uint32_t u; } v; v.f = f;
    uint32_t u = v.u;
    uint32_t r = (u + 0x7fffu + ((u >> 16) & 1u)) >> 16;   // RNE
    return (unsigned short)r;
}
static __device__ __forceinline__ unsigned short f2h(float f) {
    union { _Float16 h; unsigned short u; } v; v.h = (_Float16)f; return v.u;
}
static __device__ __forceinline__ float h2f(unsigned short u) {
    union { _Float16 h; unsigned short u; } v; v.u = u; return (float)v.h;
}
static __device__ __forceinline__ float sigf(float x) {
    return 1.0f / (1.0f + __expf(-x));
}
static __device__ __forceinline__ float tanhfast(float x) {
    return 2.0f / (1.0f + __expf(-2.0f * x)) - 1.0f;
}

#define GLOAD_LDS16(gsrc, ldst)                                                       \
    __builtin_amdgcn_global_load_lds((const __attribute__((address_space(1))) void*)(gsrc), \
                                     (__attribute__((address_space(3))) void*)(ldst), \
                                     16, 0, 0)

// ---------------------------------------------------------------- merged prep kernel
// bid < 24576            : x fp32 -> bf16
// 24576 <= bid < 27648   : Wih transpose + mode-1 gate perm (K=768)
// 27648 <= bid < 31744   : Whh transpose + mode-1 gate perm (K=1024)
// mode-1 perm: original col n = g*1024 + j -> row n' = (j>>4)*64 + g*16 + (j&15)
// (within any 128-row slice of Wt: 32 units as [u16(2)][gate(4)][u16(16)])

__global__ void prep_kernel(const float* __restrict__ x, unsigned short* __restrict__ xbf,
                            const float* __restrict__ Wih, unsigned short* __restrict__ wih_t,
                            const float* __restrict__ Whh, unsigned short* __restrict__ whh_t) {
    const int bid = blockIdx.x;
    const int tid = threadIdx.x;
    if (bid < 24576) {
        int idx = bid * 256 + tid;      // B*T*F/4 float4
        float4 v = *(const float4*)(x + (size_t)idx * 4);
        ushort4 o;
        o.x = f2bf(v.x); o.y = f2bf(v.y); o.z = f2bf(v.z); o.w = f2bf(v.w);
        *(ushort4*)(xbf + (size_t)idx * 4) = o;
        return;
    }
    __shared__ float tile[32][33];
    const float* w;
    unsigned short* wt;
    int K, idx;
    if (bid < 24576 + 3072) { w = Wih; wt = wih_t; K = F_; idx = bid - 24576; }
    else                    { w = Whh; wt = whh_t; K = H_; idx = bid - 27648; }
    int nb = (idx & 127) * 32;          // over 4096
    int kb = (idx >> 7) * 32;           // over K
    int tx = tid & 31, ty = tid >> 5;   // 32 x 8
    #pragma unroll
    for (int i = 0; i < 32; i += 8)
        tile[ty + i][tx] = w[(size_t)(kb + ty + i) * G4_ + nb + tx];
    __syncthreads();
    #pragma unroll
    for (int i = 0; i < 32; i += 8) {
        int n = nb + ty + i;
        int g = n >> 10;
        int j = n & 1023;
        int np = (j >> 4) * 64 + g * 16 + (j & 15);
        wt[(size_t)np * K + kb + tx] = f2bf(tile[tx][ty + i]);
    }
}

// ---------------------------------------------------------------- shared GEMM macros
// BM=64, BN=128, BK=64, 256 thr = 4 waves (2m x 2n), wave tile 32x64.
//   m-frag mm (0..1): row = wm*32 + mm*16 + fr
//   n-frag nf (0..3): col = wn*64 + nf*16 + fr   (nf == gate, mode-1 perm)
// LDS 72KB: A[3][64][64], B[3][128][64]; slot(kt)=kt%3; 16B-chunk XOR swizzle.
// Single-phase K-tile schedule (determinism-proven r8/r9/r10):
//   { ds_read(kt) | gload(kt+2 -> slot (kt+2)%3) | lgkm0 | MFMA | vmcnt(6) | bar }

#define STG_A(slot, srcp, ld, base, kt) do {                                          \
    const int kel_ = (kt) * 64;                                                       \
    _Pragma("unroll")                                                                 \
    for (int r2 = 0; r2 < 2; ++r2) {                                                  \
        const int rih_ = r2 * 32 + (tid >> 3);                                        \
        const int ch_  = (tid & 7) ^ (rih_ & 7);                                      \
        GLOAD_LDS16((srcp) + (size_t)((base) + rih_) * (ld) + kel_ + ch_ * 8,         \
                    &ldsA[slot][r2 * 2048 + tid * 8]);                                \
    }                                                                                 \
} while (0)

#define STG_B(slot, srcp, ld, base, kt) do {                                          \
    const int kel_ = (kt) * 64;                                                       \
    _Pragma("unroll")                                                                 \
    for (int r4 = 0; r4 < 4; ++r4) {                                                  \
        const int rih_ = r4 * 32 + (tid >> 3);                                        \
        const int ch_  = (tid & 7) ^ (rih_ & 7);                                      \
        GLOAD_LDS16((srcp) + (size_t)((base) + rih_) * (ld) + kel_ + ch_ * 8,         \
                    &ldsB[slot][r4 * 2048 + tid * 8]);                                \
    }                                                                                 \
} while (0)

#define RD_A6(slot, AR)                                                               \
    _Pragma("unroll")                                                                 \
    for (int mm = 0; mm < 2; ++mm) {                                                  \
        const int row_ = wm * 32 + mm * 16 + fr;                                      \
        _Pragma("unroll")                                                             \
        for (int kk = 0; kk < 2; ++kk)                                                \
            AR[mm][kk] = *(const bf16x8*)&ldsA[slot]                                  \
                [row_ * 64 + (((kk * 4 + fq) ^ (row_ & 7)) * 8)];                     \
    }

#define RD_B6(slot, BF)                                                               \
    _Pragma("unroll")                                                                 \
    for (int nf = 0; nf < 4; ++nf) {                                                  \
        const int rowb_ = wn * 64 + nf * 16 + fr;                                     \
        _Pragma("unroll")                                                             \
        for (int kk = 0; kk < 2; ++kk)                                                \
            BF[nf][kk] = *(const bf16x8*)&ldsB[slot]                                  \
                [rowb_ * 64 + (((kk * 4 + fq) ^ (rowb_ & 7)) * 8)];                   \
    }

#define MFMA16S(AR, BF)                                                               \
    __builtin_amdgcn_s_setprio(1);                                                    \
    _Pragma("unroll")                                                                 \
    for (int mm = 0; mm < 2; ++mm)                                                    \
        _Pragma("unroll")                                                             \
        for (int nf = 0; nf < 4; ++nf)                                                \
            _Pragma("unroll")                                                         \
            for (int kk = 0; kk < 2; ++kk)                                            \
                acc[mm][nf] = __builtin_amdgcn_mfma_f32_16x16x32_bf16(                \
                    AR[mm][kk], BF[nf][kk], acc[mm][nf], 0, 0, 0);                    \
    __builtin_amdgcn_s_setprio(0);

#define LGKM0 asm volatile("s_waitcnt lgkmcnt(0)" ::: "memory");
#define WAIT6 asm volatile("s_waitcnt vmcnt(6)" ::: "memory");
#define BARR  __builtin_amdgcn_s_barrier();

// x-slice GEMM body (K=768, 12 tiles): acc[2][4] += x_t[64 rows] @ Wih_perm[128 cols]
#define XGEMM_BODY(tslice, bm0x, bn0x)                                                \
    const unsigned short* srcax = xbf + (size_t)(tslice) * F_;                        \
    STG_A(0, srcax, TF_, bm0x, 0); STG_B(0, wih_t, F_, bn0x, 0);                      \
    STG_A(1, srcax, TF_, bm0x, 1); STG_B(1, wih_t, F_, bn0x, 1);                      \
    WAIT6; BARR;                                                                      \
    for (int kt = 0; kt < 12; ++kt) {                                                 \
        const int s_ = kt % 3, s2_ = (kt + 2) % 3;                                    \
        const int k2_ = (kt + 2 < 12) ? kt + 2 : 11;                                  \
        bf16x8 Am[2][2], Bf[4][2];                                                    \
        RD_A6(s_, Am); RD_B6(s_, Bf);                                                 \
        STG_A(s2_, srcax, TF_, bm0x, k2_);                                            \
        STG_B(s2_, wih_t, F_, bn0x, k2_);                                             \
        LGKM0;                                                                        \
        MFMA16S(Am, Bf);                                                              \
        WAIT6; BARR;                                                                  \
    }

// ---------------------------------------------------------------- upfront x-slices
// grid 2048: blocks [0,1024) -> t=0 with fused cell0 (gx[0] never stored);
//            blocks [1024,2048) -> t=1, store gx[1].

__global__ __launch_bounds__(256, 2) void xslice_kernel(
        const unsigned short* __restrict__ xbf,    // [B][T][F] bf16
        const unsigned short* __restrict__ wih_t,  // [4096][768] bf16 perm
        unsigned short* __restrict__ gx,           // [16][2048][1024][4] f16
        const float* __restrict__ bias,
        float* __restrict__ c,                     // t=0 init
        unsigned short* __restrict__ hbf0) {       // h0
    __shared__ __align__(16) unsigned short ldsA[3][4096];
    __shared__ __align__(16) unsigned short ldsB[3][8192];

    const int tid = threadIdx.x;
    const int wid = tid >> 6, lane = tid & 63;
    const int wm = wid >> 1, wn = wid & 1;
    const int fr = lane & 15, fq = lane >> 4;

    const int bid = blockIdx.x;
    const int t01 = bid >> 10;
    const int xid = bid & 1023;
    const int xcd = xid & 7;
    const int ii  = xid >> 3;                 // 0..127
    const int bnx = xcd * 4 + (ii & 3);       // 0..31
    const int bmx = ii >> 2;                  // 0..31
    const int bm0x = bmx * 64, bn0x = bnx * 128;

    f32x4 acc[2][4] = {};
    XGEMM_BODY(t01, bm0x, bn0x)

    const int j = (bnx * 2 + wn) * 16 + fr;   // hidden unit
    if (t01 == 1) {
        #pragma unroll
        for (int mm = 0; mm < 2; ++mm) {
            #pragma unroll
            for (int rr = 0; rr < 4; ++rr) {
                int row = bm0x + wm * 32 + mm * 16 + fq * 4 + rr;
                ushort4 o;
                o.x = f2h(acc[mm][0][rr]);
                o.y = f2h(acc[mm][1][rr]);
                o.z = f2h(acc[mm][2][rr]);
                o.w = f2h(acc[mm][3][rr]);
                *(ushort4*)(gx + (((size_t)1 * B_ + row) * H_ + j) * 4) = o;
            }
        }
    } else {
        // fused cell0 (c_old = 0); gate values pass through f16 to keep
        // numerics identical to the materialized-gx path
        const float bi = bias[j], bg = bias[2 * H_ + j], bo = bias[3 * H_ + j];
        #pragma unroll
        for (int mm = 0; mm < 2; ++mm) {
            #pragma unroll
            for (int rr = 0; rr < 4; ++rr) {
                int row = bm0x + wm * 32 + mm * 16 + fq * 4 + rr;
                float gi = bi + h2f(f2h(acc[mm][0][rr]));
                float gg = bg + h2f(f2h(acc[mm][2][rr]));
                float go = bo + h2f(f2h(acc[mm][3][rr]));
                float cn = sigf(gi) * tanhfast(gg);
                float hv = sigf(go) * tanhfast(cn);
                size_t off = (size_t)row * H_ + j;
                c[off] = cn;
                hbf0[off] = f2bf(hv);
            }
        }
    }
}

// ---------------------------------------------------------------- fused step
// grid 1536 (t=1..14) / 512 (t=15).  bid%3==0 -> step block (sid=bid/3),
// else xgemm block computing gx[t+1] (consumed by the NEXT launch; stream
// ordering is the producer/consumer barrier).  Interleaving spreads both
// block types across CUs so xgemm work soaks the step blocks' latency bubbles.

__global__ __launch_bounds__(256, 2) void lstm_fused_kernel(
        const unsigned short* __restrict__ hprev,  // [2048][1024] bf16
        const unsigned short* __restrict__ whh_t,  // [4096][1024] bf16 perm
        const unsigned short* __restrict__ xbf,    // [B][T][F] bf16
        const unsigned short* __restrict__ wih_t,  // [4096][768] bf16 perm
        unsigned short* __restrict__ gx,           // [16][2048][1024][4] f16
        const float* __restrict__ bias,
        float* __restrict__ c,                     // [2048][1024] f32 r/w
        unsigned short* __restrict__ hnext,        // [2048][1024] bf16
        float* __restrict__ hout,                  // [2048][1024] f32 (last)
        int t, int last, int has_x) {
    __shared__ __align__(16) unsigned short ldsA[3][4096];   // 24 KB
    __shared__ __align__(16) unsigned short ldsB[3][8192];   // 48 KB

    const int tid = threadIdx.x;
    const int wid = tid >> 6, lane = tid & 63;
    const int wm = wid >> 1, wn = wid & 1;
    const int fr = lane & 15, fq = lane >> 4;

    const int bid = blockIdx.x;
    int sid = bid, is_step = 1;
    if (has_x) { is_step = ((bid % 3) == 0); sid = bid / 3; }

    if (is_step) {
        // ==== round-10/11 panel-merged step path (verbatim, sid-indexed) ====
        const int xcd = sid & 7;
        const int i   = sid >> 3;                 // 0..63
        const int pair = i & 1;
        const int bm  = i >> 1;                   // 0..31
        const int bn_base = xcd * 4 + pair * 2;   // panels bn_base, bn_base+1
        const int bm0 = bm * 64;

        const int j0 = (bn_base * 2 + wn) * 16 + fr;
        const int j1 = ((bn_base + 1) * 2 + wn) * 16 + fr;
        const float bi0 = bias[j0], bf0 = bias[H_ + j0], bg0 = bias[2 * H_ + j0], bo0 = bias[3 * H_ + j0];
        const float bi1 = bias[j1], bf1 = bias[H_ + j1], bg1 = bias[2 * H_ + j1], bo1 = bias[3 * H_ + j1];

        f32x4 acc[2][4] = {};
        ushort4 gpre[2][4];
        float   cpre[2][4];

        STG_A(0, hprev, H_, bm0, 0); STG_B(0, whh_t, H_, bn_base * 128, 0);
        STG_A(1, hprev, H_, bm0, 1); STG_B(1, whh_t, H_, bn_base * 128, 1);
        WAIT6; BARR;

        for (int kt = 0; kt < 32; ++kt) {
            const int s_  = kt % 3;
            const int s2_ = (kt + 2) % 3;
            const int k2  = (kt + 2 < 32) ? kt + 2 : 31;
            const int ak2 = k2 & 15;                               // A repeats per panel
            const int brb2 = (bn_base + (k2 >> 4)) * 128;          // B base of staged tile
            bf16x8 Am[2][2], Bf[4][2];
            RD_A6(s_, Am);
            RD_B6(s_, Bf);
            STG_A(s2_, hprev, H_, bm0, ak2);
            STG_B(s2_, whh_t, H_, brb2, ak2);
            if (kt == 13 || kt == 29) {
                const int p_ = kt >> 4;
                const int jp_ = p_ ? j1 : j0;
                #pragma unroll
                for (int mm = 0; mm < 2; ++mm)
                    #pragma unroll
                    for (int rr = 0; rr < 4; ++rr) {
                        int row_ = bm0 + wm * 32 + mm * 16 + fq * 4 + rr;
                        gpre[mm][rr] = *(const ushort4*)(gx + (((size_t)t * B_ + row_) * H_ + jp_) * 4);
                        cpre[mm][rr] = c[(size_t)row_ * H_ + jp_];
                    }
            }
            LGKM0;
            MFMA16S(Am, Bf);
            if (kt == 13 || kt == 14 || kt == 29 || kt == 30)
                asm volatile("s_waitcnt vmcnt(22)" ::: "memory");
            else
                asm volatile("s_waitcnt vmcnt(6)" ::: "memory");
            BARR;
            if (kt == 15) {
                #pragma unroll
                for (int mm = 0; mm < 2; ++mm) {
                    #pragma unroll
                    for (int rr = 0; rr < 4; ++rr) {
                        int row_ = bm0 + wm * 32 + mm * 16 + fq * 4 + rr;
                        ushort4 g4 = gpre[mm][rr];
                        float gi = acc[mm][0][rr] + bi0 + h2f(g4.x);
                        float gf = acc[mm][1][rr] + bf0 + h2f(g4.y);
                        float gg = acc[mm][2][rr] + bg0 + h2f(g4.z);
                        float go = acc[mm][3][rr] + bo0 + h2f(g4.w);
                        float cn = sigf(gf) * cpre[mm][rr] + sigf(gi) * tanhfast(gg);
                        float hv = sigf(go) * tanhfast(cn);
                        size_t off = (size_t)row_ * H_ + j0;
                        c[off] = cn;
                        hnext[off] = f2bf(hv);
                        if (last) hout[off] = hv;
                    }
                }
                #pragma unroll
                for (int mm = 0; mm < 2; ++mm)
                    #pragma unroll
                    for (int nf = 0; nf < 4; ++nf)
                        #pragma unroll
                        for (int q = 0; q < 4; ++q) acc[mm][nf][q] = 0.0f;
            }
        }

        #pragma unroll
        for (int mm = 0; mm < 2; ++mm) {
            #pragma unroll
            for (int rr = 0; rr < 4; ++rr) {
                int row_ = bm0 + wm * 32 + mm * 16 + fq * 4 + rr;
                ushort4 g4 = gpre[mm][rr];
                float gi = acc[mm][0][rr] + bi1 + h2f(g4.x);
                float gf = acc[mm][1][rr] + bf1 + h2f(g4.y);
                float gg = acc[mm][2][rr] + bg1 + h2f(g4.z);
                float go = acc[mm][3][rr] + bo1 + h2f(g4.w);
                float cn = sigf(gf) * cpre[mm][rr] + sigf(gi) * tanhfast(gg);
                float hv = sigf(go) * tanhfast(cn);
                size_t off = (size_t)row_ * H_ + j1;
                c[off] = cn;
                hnext[off] = f2bf(hv);
                if (last) hout[off] = hv;
            }
        }
    } else {
        // ==== xgemm block: gx[t+1] slice (no dependency on h/c) ====
        const int xid = bid - bid / 3 - 1;        // 0..1023
        const int xcd = xid & 7;
        const int ii  = xid >> 3;                 // 0..127
        const int bnx = xcd * 4 + (ii & 3);       // 0..31
        const int bmx = ii >> 2;                  // 0..31
        const int bm0x = bmx * 64, bn0x = bnx * 128;

        f32x4 acc[2][4] = {};
        XGEMM_BODY(t + 1, bm0x, bn0x)

        const int j = (bnx * 2 + wn) * 16 + fr;
        #pragma unroll
        for (int mm = 0; mm < 2; ++mm) {
            #pragma unroll
            for (int rr = 0; rr < 4; ++rr) {
                int row = bm0x + wm * 32 + mm * 16 + fq * 4 + rr;
                ushort4 o;
                o.x = f2h(acc[mm][0][rr]);
                o.y = f2h(acc[mm][1][rr]);
                o.z = f2h(acc[mm][2][rr]);
                o.w = f2h(acc[mm][3][rr]);
                *(ushort4*)(gx + (((size_t)(t + 1) * B_ + row) * H_ + j) * 4) = o;
            }
        }
    }
}

// ---------------------------------------------------------------- launch

extern "C" void kernel_launch(void* const* d_in, const int* in_sizes, int n_in,
                              void* d_out, int out_size, void* d_ws, size_t ws_size,
                              hipStream_t stream) {
    const float* x    = (const float*)d_in[0];   // [B,T,F]
    const float* Wih  = (const float*)d_in[1];   // [F,4H]
    const float* Whh  = (const float*)d_in[2];   // [H,4H]
    const float* bias = (const float*)d_in[3];   // [4H]
    float* out = (float*)d_out;                  // [B,H] flat

    char* ws = (char*)d_ws;
    unsigned short* xbf   = (unsigned short*)(ws);               // 50,331,648 B
    unsigned short* wih_t = (unsigned short*)(ws + 50331648);    //  6,291,456
    unsigned short* whh_t = (unsigned short*)(ws + 56623104);    //  8,388,608
    unsigned short* hbf0  = (unsigned short*)(ws + 65011712);    //  4,194,304
    unsigned short* hbf1  = (unsigned short*)(ws + 69206016);    //  4,194,304
    float*          c     = (float*)(ws + 73400320);             //  8,388,608
    unsigned short* gx    = (unsigned short*)(ws + 81788928);    // 268,435,456
    // total 350,224,384 B <= ws_size

    // merged prep: convert x + both W transposes (mode-1 perm) in one launch
    hipLaunchKernelGGL(prep_kernel, dim3(24576 + 3072 + 4096), dim3(256), 0, stream,
                       x, xbf, Wih, wih_t, Whh, whh_t);

    // upfront x-slices: t=0 (fused cell0 -> c,h0) and t=1 (gx[1])
    hipLaunchKernelGGL(xslice_kernel, dim3(2048), dim3(256), 0, stream,
                       xbf, wih_t, gx, bias, c, hbf0);

    // t = 1..15: recurrent step + (t<15) next-slice xgemm riding along
    for (int t = 1; t < T_; ++t) {
        unsigned short* hr = (t & 1) ? hbf0 : hbf1;
        unsigned short* hw = (t & 1) ? hbf1 : hbf0;
        int has_x = (t < T_ - 1) ? 1 : 0;
        int grid  = has_x ? 1536 : 512;
        hipLaunchKernelGGL(lstm_fused_kernel, dim3(grid), dim3(256), 0, stream,
                           hr, whh_t, xbf, wih_t, gx, bias, c, hw, out,
                           t, (t == T_ - 1) ? 1 : 0, has_x);
    }
}

// Round 13
// 724.947 us; speedup vs baseline: 1.3859x; 1.3859x over previous
//
#include <hip/hip_runtime.h>
#include <hip/hip_bf16.h>
#include <stdint.h>

#define B_  2048
#define T_  16
#define F_  768
#define H_  1024
#define G4_ 4096   // 4*H

typedef __attribute__((ext_vector_type(8))) __bf16 bf16x8;
typedef __attribute__((ext_vector_type(4))) float  f32x4;

static __device__ __forceinline__ unsigned short f2bf(float f) {
    union { float f; uint32_t u; } v; v.f = f;
    uint32_t u = v.u;
    uint32_t r = (u + 0x7fffu + ((u >> 16) & 1u)) >> 16;   // RNE
    return (unsigned short)r;
}
static __device__ __forceinline__ unsigned short f2h(float f) {
    union { _Float16 h; unsigned short u; } v; v.h = (_Float16)f; return v.u;
}
static __device__ __forceinline__ float h2f(unsigned short u) {
    union { _Float16 h; unsigned short u; } v; v.u = u; return (float)v.h;
}
static __device__ __forceinline__ float sigf(float x) {
    return 1.0f / (1.0f + __expf(-x));
}
static __device__ __forceinline__ float tanhfast(float x) {
    return 2.0f / (1.0f + __expf(-2.0f * x)) - 1.0f;
}

#define GLOAD_LDS16(gsrc, ldst)                                                       \
    __builtin_amdgcn_global_load_lds((const __attribute__((address_space(1))) void*)(gsrc), \
                                     (__attribute__((address_space(3))) void*)(ldst), \
                                     16, 0, 0)

// ---------------------------------------------------------------- merged prep kernel
// bid < 24576            : x fp32 -> bf16
// 24576 <= bid < 27648   : Wih transpose+perm mode0 (for 8-wave xgemm)
// 27648 <= bid < 31744   : Whh transpose+perm mode1 (for 4-wave steps)
// mode 0: n' = (j>>6)*256 + g*64 + ((j>>4)&3)*16 + (j&15)
// mode 1: n' = (j>>4)*64  + g*16 + (j&15)

__global__ void prep_kernel(const float* __restrict__ x, unsigned short* __restrict__ xbf,
                            const float* __restrict__ Wih, unsigned short* __restrict__ wih_t,
                            const float* __restrict__ Whh, unsigned short* __restrict__ whh_t) {
    const int bid = blockIdx.x;
    const int tid = threadIdx.x;
    if (bid < 24576) {
        int idx = bid * 256 + tid;      // B*T*F/4 float4
        float4 v = *(const float4*)(x + (size_t)idx * 4);
        ushort4 o;
        o.x = f2bf(v.x); o.y = f2bf(v.y); o.z = f2bf(v.z); o.w = f2bf(v.w);
        *(ushort4*)(xbf + (size_t)idx * 4) = o;
        return;
    }
    __shared__ float tile[32][33];
    const float* w;
    unsigned short* wt;
    int K, mode, idx;
    if (bid < 24576 + 3072) { w = Wih; wt = wih_t; K = F_; mode = 0; idx = bid - 24576; }
    else                    { w = Whh; wt = whh_t; K = H_; mode = 1; idx = bid - 27648; }
    int nb = (idx & 127) * 32;          // over 4096
    int kb = (idx >> 7) * 32;           // over K
    int tx = tid & 31, ty = tid >> 5;   // 32 x 8
    #pragma unroll
    for (int i = 0; i < 32; i += 8)
        tile[ty + i][tx] = w[(size_t)(kb + ty + i) * G4_ + nb + tx];
    __syncthreads();
    #pragma unroll
    for (int i = 0; i < 32; i += 8) {
        int n = nb + ty + i;
        int g = n >> 10;
        int j = n & 1023;
        int np = mode ? ((j >> 4) * 64 + g * 16 + (j & 15))
                      : ((j >> 6) * 256 + g * 64 + ((j >> 4) & 3) * 16 + (j & 15));
        wt[(size_t)np * K + kb + tx] = f2bf(tile[tx][ty + i]);
    }
}

// ================================================================ 8-phase 256^2 xgemm, M-merged x4
// grid 512, each block: 4 M-tiles (1024 rows) x 1 N-panel over one continuous
// 48-tile pipeline.  A base advances every 12 tiles (each element read once);
// B repeats kt%12 and re-stages from its L2-resident 0.4 MB panel.  Boundary
// epilogue (EPIX + acc reset) at kt%12==11; stores between barriers only
// strengthen the following counted vmcnt (over-wait, safe).  Fused t=0 cell.

#define STAGE4(bufi, kind, half, gbase, ld, rowbase, kt) do {                         \
    const int kel_ = (kt) * 64;                                                       \
    _Pragma("unroll")                                                                 \
    for (int r2 = 0; r2 < 2; ++r2) {                                                  \
        const int rih_ = r2 * 64 + (tid >> 3);                                        \
        const int ch_  = (tid & 7) ^ (rih_ & 7);                                      \
        GLOAD_LDS16((gbase) + (size_t)((rowbase) + (half) * 128 + rih_) * (ld)        \
                            + kel_ + ch_ * 8,                                         \
                    &lds[bufi][kind][half][r2 * 4096 + tid * 8]);                     \
    }                                                                                 \
} while (0)

#define RD4_A(half_, mb)                                                              \
    _Pragma("unroll")                                                                 \
    for (int mm = 0; mm < 4; ++mm) {                                                  \
        const int row_ = ((mb) + mm) * 32 + wm * 16 + fr;                             \
        _Pragma("unroll")                                                             \
        for (int kk = 0; kk < 2; ++kk)                                                \
            Afr[mm][kk] = *(const bf16x8*)&lds[buf][0][half_]                         \
                [(row_ & 127) * 64 + (((kk * 4 + fq) ^ (row_ & 7)) * 8)];             \
    }

#define RD4_B(half_, nb)                                                              \
    _Pragma("unroll")                                                                 \
    for (int nn = 0; nn < 2; ++nn) {                                                  \
        const int row_ = ((nb) + nn) * 64 + wn * 16 + fr;                             \
        _Pragma("unroll")                                                             \
        for (int kk = 0; kk < 2; ++kk)                                                \
            Bfr[(nb) + nn][kk] = *(const bf16x8*)&lds[buf][1][half_]                  \
                [(row_ & 127) * 64 + (((kk * 4 + fq) ^ (row_ & 7)) * 8)];             \
    }

#define MFMAQ(mb, nb)                                                                 \
    __builtin_amdgcn_s_setprio(1);                                                    \
    _Pragma("unroll")                                                                 \
    for (int mm = 0; mm < 4; ++mm)                                                    \
        _Pragma("unroll")                                                             \
        for (int nn = 0; nn < 2; ++nn)                                                \
            _Pragma("unroll")                                                         \
            for (int kk = 0; kk < 2; ++kk)                                            \
                acc[(mb) + mm][(nb) + nn] = __builtin_amdgcn_mfma_f32_16x16x32_bf16(  \
                    Afr[mm][kk], Bfr[(nb) + nn][kk], acc[(mb) + mm][(nb) + nn], 0, 0, 0); \
    __builtin_amdgcn_s_setprio(0);

#define WAITV4  asm volatile("s_waitcnt vmcnt(10)" ::: "memory");                     \
                __builtin_amdgcn_sched_barrier(0);
#define BARR4   __builtin_amdgcn_s_barrier();                                         \
                __builtin_amdgcn_sched_barrier(0);

// epilogue for one 256-row M-tile (base row mbase); fused cell0 for t=0 rows
#define EPIX_M(mbase)                                                                 \
    {                                                                                 \
        _Pragma("unroll")                                                             \
        for (int mm = 0; mm < 8; ++mm) {                                              \
            _Pragma("unroll")                                                         \
            for (int rr = 0; rr < 4; ++rr) {                                          \
                int row_ = (mbase) + mm * 32 + wm * 16 + fq * 4 + rr;                 \
                int tt_ = row_ & 15, bb_ = row_ >> 4;                                 \
                ushort4 o_;                                                           \
                o_.x = f2h(acc[mm][0][rr]);                                           \
                o_.y = f2h(acc[mm][1][rr]);                                           \
                o_.z = f2h(acc[mm][2][rr]);                                           \
                o_.w = f2h(acc[mm][3][rr]);                                           \
                if (tt_ != 0) {                                                       \
                    *(ushort4*)(gx + (((size_t)tt_ * B_ + bb_) * H_ + j) * 4) = o_;   \
                } else {                                                              \
                    float gi_ = bi_ + h2f(o_.x);                                      \
                    float gg_ = bg_ + h2f(o_.z);                                      \
                    float go_ = bo_ + h2f(o_.w);                                      \
                    float cn_ = sigf(gi_) * tanhfast(gg_);                            \
                    float hv_ = sigf(go_) * tanhfast(cn_);                            \
                    size_t off_ = (size_t)bb_ * H_ + j;                               \
                    c[off_] = cn_;                                                    \
                    hbf0[off_] = f2bf(hv_);                                           \
                }                                                                     \
            }                                                                         \
        }                                                                             \
    }

__global__ __launch_bounds__(512, 2) void xgemm8m_kernel(
        const unsigned short* __restrict__ xbf,    // [32768][768] bf16 (m = b*16+t)
        const unsigned short* __restrict__ wih_t,  // [4096][768]  bf16 perm mode0
        unsigned short* __restrict__ gx,           // [16][2048][1024][4] f16
        const float* __restrict__ bias,
        float* __restrict__ c,                     // t=0 init
        unsigned short* __restrict__ hbf0) {       // h0
    __shared__ __align__(16) unsigned short lds[2][2][2][8192];   // 128 KB

    // XCD-aware: xcd owns 2 bn (B panels 0.8MB L2-resident); M-groups stream
    const int bid = blockIdx.x;               // 0..511
    const int xcd = bid & 7;
    const int i   = bid >> 3;                 // 0..63
    const int bn  = xcd * 2 + (i & 1);        // 0..15
    const int mg  = i >> 1;                   // 0..31
    const int bmb = mg * 1024;                // first row of this block's 4 M-tiles
    const int bn0 = bn * 256;

    const int tid = threadIdx.x;
    const int wid = tid >> 6, lane = tid & 63;
    const int wm = wid >> 2, wn = wid & 3;
    const int fr = lane & 15, fq = lane >> 4;

    const int j = bn * 64 + wn * 16 + fr;
    float bi_ = 0.f, bg_ = 0.f, bo_ = 0.f;
    if (fq == 0) {                       // only fq==0 threads own t=0 rows
        bi_ = bias[j]; bg_ = bias[2 * H_ + j]; bo_ = bias[3 * H_ + j];
    }

    f32x4 acc[8][4] = {};

    // prologue: tiles 0,1 (M-tile 0)
    STAGE4(0, 0, 0, xbf, F_, bmb, 0);
    STAGE4(0, 1, 0, wih_t, F_, bn0, 0);
    STAGE4(0, 1, 1, wih_t, F_, bn0, 0);
    STAGE4(0, 0, 1, xbf, F_, bmb, 0);
    STAGE4(1, 0, 0, xbf, F_, bmb, 1);
    STAGE4(1, 1, 0, wih_t, F_, bn0, 1);
    STAGE4(1, 1, 1, wih_t, F_, bn0, 1);
    WAITV4; BARR4;

    for (int kt = 0; kt < 48; ++kt) {
        const int buf = kt & 1, nbuf = buf ^ 1;
        const int k1 = (kt + 1 < 48) ? kt + 1 : 47;
        const int k2 = (kt + 2 < 48) ? kt + 2 : 47;
        const int a1b = bmb + (k1 / 12) * 256, a1k = k1 % 12;   // A of tile k1
        const int a2b = bmb + (k2 / 12) * 256, a2k = k2 % 12;   // A of tile k2
        const int b2k = k2 % 12;                                // B repeats per M-tile
        bf16x8 Afr[4][2]; bf16x8 Bfr[4][2];
        /* ph0 */
        RD4_A(0, 0); RD4_B(0, 0);
        STAGE4(nbuf, 0, 1, xbf, F_, a1b, a1k);
        WAITV4; BARR4;
        MFMAQ(0, 0); BARR4;
        /* ph1 */
        RD4_B(1, 2);
        STAGE4(buf, 0, 0, xbf, F_, a2b, a2k);
        WAITV4; BARR4;
        MFMAQ(0, 2); BARR4;
        /* ph2 */
        RD4_A(1, 4);
        STAGE4(buf, 1, 0, wih_t, F_, bn0, b2k);
        BARR4;
        MFMAQ(4, 0); BARR4;
        /* ph3 */
        STAGE4(buf, 1, 1, wih_t, F_, bn0, b2k);
        WAITV4; BARR4;
        MFMAQ(4, 2); BARR4;
        /* M-tile boundary: dump + reset (registers/global only) */
        if ((kt % 12) == 11) {
            EPIX_M(bmb + (kt / 12) * 256);
            #pragma unroll
            for (int mm = 0; mm < 8; ++mm)
                #pragma unroll
                for (int nf = 0; nf < 4; ++nf)
                    #pragma unroll
                    for (int q = 0; q < 4; ++q) acc[mm][nf][q] = 0.0f;
        }
    }
}

// ================================================================ recurrent step
// (round-10/11 kernel verbatim; measured ~30.7 us/step)

#define STA6(slot, kt) do {                                                           \
    const int kel_ = (kt) * 64;                                                       \
    _Pragma("unroll")                                                                 \
    for (int r2 = 0; r2 < 2; ++r2) {                                                  \
        const int rih_ = r2 * 32 + (tid >> 3);                                        \
        const int ch_  = (tid & 7) ^ (rih_ & 7);                                      \
        GLOAD_LDS16(hprev + (size_t)(bm0 + rih_) * H_ + kel_ + ch_ * 8,               \
                    &ldsA[slot][r2 * 2048 + tid * 8]);                                \
    }                                                                                 \
} while (0)

#define STB6(slot, rowbase, kt) do {                                                  \
    const int kel_ = (kt) * 64;                                                       \
    _Pragma("unroll")                                                                 \
    for (int r4 = 0; r4 < 4; ++r4) {                                                  \
        const int rih_ = r4 * 32 + (tid >> 3);                                        \
        const int ch_  = (tid & 7) ^ (rih_ & 7);                                      \
        GLOAD_LDS16(whh_t + (size_t)((rowbase) + rih_) * H_ + kel_ + ch_ * 8,         \
                    &ldsB[slot][r4 * 2048 + tid * 8]);                                \
    }                                                                                 \
} while (0)

#define RD_A6(slot, AR)                                                               \
    _Pragma("unroll")                                                                 \
    for (int mm = 0; mm < 2; ++mm) {                                                  \
        const int row_ = wm * 32 + mm * 16 + fr;                                      \
        _Pragma("unroll")                                                             \
        for (int kk = 0; kk < 2; ++kk)                                                \
            AR[mm][kk] = *(const bf16x8*)&ldsA[slot]                                  \
                [row_ * 64 + (((kk * 4 + fq) ^ (row_ & 7)) * 8)];                     \
    }

#define RD_B6(slot, BF)                                                               \
    _Pragma("unroll")                                                                 \
    for (int nf = 0; nf < 4; ++nf) {                                                  \
        const int rowb_ = wn * 64 + nf * 16 + fr;                                     \
        _Pragma("unroll")                                                             \
        for (int kk = 0; kk < 2; ++kk)                                                \
            BF[nf][kk] = *(const bf16x8*)&ldsB[slot]                                  \
                [rowb_ * 64 + (((kk * 4 + fq) ^ (rowb_ & 7)) * 8)];                   \
    }

#define MFMA16S(AR, BF)                                                               \
    __builtin_amdgcn_s_setprio(1);                                                    \
    _Pragma("unroll")                                                                 \
    for (int mm = 0; mm < 2; ++mm)                                                    \
        _Pragma("unroll")                                                             \
        for (int nf = 0; nf < 4; ++nf)                                                \
            _Pragma("unroll")                                                         \
            for (int kk = 0; kk < 2; ++kk)                                            \
                acc[mm][nf] = __builtin_amdgcn_mfma_f32_16x16x32_bf16(                \
                    AR[mm][kk], BF[nf][kk], acc[mm][nf], 0, 0, 0);                    \
    __builtin_amdgcn_s_setprio(0);

#define LGKM0 asm volatile("s_waitcnt lgkmcnt(0)" ::: "memory");
#define BARR  __builtin_amdgcn_s_barrier();

__global__ __launch_bounds__(256, 2) void lstm_step_dp_kernel(
        const unsigned short* __restrict__ hprev,  // [2048][1024] bf16
        const unsigned short* __restrict__ whh_t,  // [4096][1024] bf16 perm mode1
        const unsigned short* __restrict__ gx,     // [16][2048][1024][4] f16
        const float* __restrict__ bias,            // [4096] original order
        float* __restrict__ c,                     // [2048][1024] f32 r/w
        unsigned short* __restrict__ hnext,        // [2048][1024] bf16
        float* __restrict__ hout,                  // [2048][1024] f32 (last)
        int t, int last) {
    __shared__ __align__(16) unsigned short ldsA[3][4096];   // 24 KB
    __shared__ __align__(16) unsigned short ldsB[3][8192];   // 48 KB

    const int bid = blockIdx.x;               // 0..511
    const int xcd = bid & 7;
    const int i   = bid >> 3;                 // 0..63
    const int pair = i & 1;
    const int bm  = i >> 1;                   // 0..31
    const int bn_base = xcd * 4 + pair * 2;   // panels bn_base, bn_base+1
    const int bm0 = bm * 64;

    const int tid = threadIdx.x;
    const int wid = tid >> 6, lane = tid & 63;
    const int wm = wid >> 1, wn = wid & 1;
    const int fr = lane & 15, fq = lane >> 4;

    const int j0 = (bn_base * 2 + wn) * 16 + fr;
    const int j1 = ((bn_base + 1) * 2 + wn) * 16 + fr;
    const float bi0 = bias[j0], bf0 = bias[H_ + j0], bg0 = bias[2 * H_ + j0], bo0 = bias[3 * H_ + j0];
    const float bi1 = bias[j1], bf1 = bias[H_ + j1], bg1 = bias[2 * H_ + j1], bo1 = bias[3 * H_ + j1];

    f32x4 acc[2][4] = {};
    ushort4 gpre[2][4];
    float   cpre[2][4];

    STA6(0, 0); STB6(0, bn_base * 128, 0);
    STA6(1, 1); STB6(1, bn_base * 128, 1);
    asm volatile("s_waitcnt vmcnt(6)" ::: "memory");
    BARR;

    for (int kt = 0; kt < 32; ++kt) {
        const int s_  = kt % 3;
        const int s2_ = (kt + 2) % 3;
        const int k2  = (kt + 2 < 32) ? kt + 2 : 31;
        const int ak2 = k2 & 15;                               // A repeats per panel
        const int brb2 = (bn_base + (k2 >> 4)) * 128;          // B base of staged tile
        bf16x8 Am[2][2], Bf[4][2];
        RD_A6(s_, Am);
        RD_B6(s_, Bf);
        STA6(s2_, ak2);
        STB6(s2_, brb2, ak2);
        if (kt == 13 || kt == 29) {
            const int p_ = kt >> 4;
            const int jp_ = p_ ? j1 : j0;
            #pragma unroll
            for (int mm = 0; mm < 2; ++mm)
                #pragma unroll
                for (int rr = 0; rr < 4; ++rr) {
                    int row_ = bm0 + wm * 32 + mm * 16 + fq * 4 + rr;
                    gpre[mm][rr] = *(const ushort4*)(gx + (((size_t)t * B_ + row_) * H_ + jp_) * 4);
                    cpre[mm][rr] = c[(size_t)row_ * H_ + jp_];
                }
        }
        LGKM0;
        MFMA16S(Am, Bf);
        if (kt == 13 || kt == 14 || kt == 29 || kt == 30)
            asm volatile("s_waitcnt vmcnt(22)" ::: "memory");
        else
            asm volatile("s_waitcnt vmcnt(6)" ::: "memory");
        BARR;
        if (kt == 15) {
            #pragma unroll
            for (int mm = 0; mm < 2; ++mm) {
                #pragma unroll
                for (int rr = 0; rr < 4; ++rr) {
                    int row_ = bm0 + wm * 32 + mm * 16 + fq * 4 + rr;
                    ushort4 g4 = gpre[mm][rr];
                    float gi = acc[mm][0][rr] + bi0 + h2f(g4.x);
                    float gf = acc[mm][1][rr] + bf0 + h2f(g4.y);
                    float gg = acc[mm][2][rr] + bg0 + h2f(g4.z);
                    float go = acc[mm][3][rr] + bo0 + h2f(g4.w);
                    float cn = sigf(gf) * cpre[mm][rr] + sigf(gi) * tanhfast(gg);
                    float hv = sigf(go) * tanhfast(cn);
                    size_t off = (size_t)row_ * H_ + j0;
                    c[off] = cn;
                    hnext[off] = f2bf(hv);
                    if (last) hout[off] = hv;
                }
            }
            #pragma unroll
            for (int mm = 0; mm < 2; ++mm)
                #pragma unroll
                for (int nf = 0; nf < 4; ++nf)
                    #pragma unroll
                    for (int q = 0; q < 4; ++q) acc[mm][nf][q] = 0.0f;
        }
    }

    #pragma unroll
    for (int mm = 0; mm < 2; ++mm) {
        #pragma unroll
        for (int rr = 0; rr < 4; ++rr) {
            int row_ = bm0 + wm * 32 + mm * 16 + fq * 4 + rr;
            ushort4 g4 = gpre[mm][rr];
            float gi = acc[mm][0][rr] + bi1 + h2f(g4.x);
            float gf = acc[mm][1][rr] + bf1 + h2f(g4.y);
            float gg = acc[mm][2][rr] + bg1 + h2f(g4.z);
            float go = acc[mm][3][rr] + bo1 + h2f(g4.w);
            float cn = sigf(gf) * cpre[mm][rr] + sigf(gi) * tanhfast(gg);
            float hv = sigf(go) * tanhfast(cn);
            size_t off = (size_t)row_ * H_ + j1;
            c[off] = cn;
            hnext[off] = f2bf(hv);
            if (last) hout[off] = hv;
        }
    }
}

// ---------------------------------------------------------------- launch

extern "C" void kernel_launch(void* const* d_in, const int* in_sizes, int n_in,
                              void* d_out, int out_size, void* d_ws, size_t ws_size,
                              hipStream_t stream) {
    const float* x    = (const float*)d_in[0];   // [B,T,F]
    const float* Wih  = (const float*)d_in[1];   // [F,4H]
    const float* Whh  = (const float*)d_in[2];   // [H,4H]
    const float* bias = (const float*)d_in[3];   // [4H]
    float* out = (float*)d_out;                  // [B,H] flat

    char* ws = (char*)d_ws;
    unsigned short* xbf   = (unsigned short*)(ws);               // 50,331,648 B
    unsigned short* wih_t = (unsigned short*)(ws + 50331648);    //  6,291,456
    unsigned short* whh_t = (unsigned short*)(ws + 56623104);    //  8,388,608
    unsigned short* hbf0  = (unsigned short*)(ws + 65011712);    //  4,194,304
    unsigned short* hbf1  = (unsigned short*)(ws + 69206016);    //  4,194,304
    float*          c     = (float*)(ws + 73400320);             //  8,388,608
    unsigned short* gx    = (unsigned short*)(ws + 81788928);    // 268,435,456
    // total 350,224,384 B <= ws_size

    // merged prep: convert x + both W transposes in one launch
    hipLaunchKernelGGL(prep_kernel, dim3(24576 + 3072 + 4096), dim3(256), 0, stream,
                       x, xbf, Wih, wih_t, Whh, whh_t);

    // input projection (all t) + fused t=0 cell, M-merged x4
    hipLaunchKernelGGL(xgemm8m_kernel, dim3(512), dim3(512), 0, stream,
                       xbf, wih_t, gx, bias, c, hbf0);

    // t = 1..15: recurrent GEMM + fused cell, panel-merged, 2 blocks/CU
    for (int t = 1; t < T_; ++t) {
        unsigned short* hr = (t & 1) ? hbf0 : hbf1;
        unsigned short* hw = (t & 1) ? hbf1 : hbf0;
        hipLaunchKernelGGL(lstm_step_dp_kernel, dim3(512), dim3(256), 0, stream,
                           hr, whh_t, gx, bias, c, hw, out, t, (t == T_ - 1) ? 1 : 0);
    }
}